// Round 3
// baseline (1551.072 us; speedup 1.0000x reference)
//
#include <hip/hip_runtime.h>

// Problem constants (fixed by reference)
constexpr int N_NEURONS  = 131072;
constexpr int X_ELEMS    = 4 * 131072 * 32;   // 16,777,216
constexpr int X4         = X_ELEMS / 4;       // 4,194,304 float4
constexpr int STATES_OFF = X_ELEMS;           // states start after x in d_out

// Fast tanh: t = 1 - 2/(e^{2|x|}+1), sign restored. Overflow-clean.
// Abs error ~1e-6 vs libm; output-0 threshold 2.5e-2. (Passed R1/R2.)
__device__ __forceinline__ float fast_tanh(float x) {
  float a = fabsf(x);
  float e = __expf(2.0f * a);
  float t = 1.0f - __fdividef(2.0f, e + 1.0f);
  return copysignf(t, x);
}

__global__ __launch_bounds__(256) void tanh4_kernel(const float* __restrict__ x,
                                                    float* __restrict__ out) {
  int idx = blockIdx.x * 256 + threadIdx.x;
  float4 v = reinterpret_cast<const float4*>(x)[idx];
  #pragma unroll
  for (int k = 0; k < 4; ++k) {
    v.x = fast_tanh(v.x);
    v.y = fast_tanh(v.y);
    v.z = fast_tanh(v.z);
    v.w = fast_tanh(v.w);
  }
  reinterpret_cast<float4*>(out)[idx] = v;
}

// States path in FP64. One thread per neuron; state in registers; weights in
// LDS as doubles (wave-uniform reads -> broadcast, conflict-free).
// fp64 error ~1e-16 is far below every threshold/top-k gap on this input
// (the fp32 jax expected passed at the 2.5e-2 floor), so no comparison flips.
__global__ __launch_bounds__(256) void enn_states_f64_kernel(
    const float* __restrict__ ns, const float* __restrict__ Wenc,
    const float* __restrict__ benc, const float* __restrict__ Wdec,
    const float* __restrict__ bdec, float* __restrict__ out) {
  __shared__ double sWenc[16 * 32];
  __shared__ double sWdec[32 * 16];
  __shared__ double sBenc[16];
  __shared__ double sBdec[32];

  const int tid = threadIdx.x;
  #pragma unroll
  for (int i = tid; i < 512; i += 256) {
    sWenc[i] = (double)Wenc[i];
    sWdec[i] = (double)Wdec[i];
  }
  if (tid < 16) sBenc[tid] = (double)benc[tid];
  if (tid < 32) sBdec[tid] = (double)bdec[tid];
  __syncthreads();

  const int n = blockIdx.x * 256 + tid;
  double s[32], ws[32];

  const float4* src = reinterpret_cast<const float4*>(ns) + (size_t)n * 8;
  #pragma unroll
  for (int j = 0; j < 8; ++j) {
    float4 v = src[j];
    s[4 * j + 0] = (double)v.x; s[4 * j + 1] = (double)v.y;
    s[4 * j + 2] = (double)v.z; s[4 * j + 3] = (double)v.w;
  }
  #pragma unroll
  for (int i = 0; i < 32; ++i) ws[i] = 0.0;

  double nrm = 0.0;
  #pragma unroll 1   // rolled: keep code small for I-cache
  for (int layer = 0; layer < 4; ++layer) {
    // sparsity (|s|>=0.01) + decay *0.9 folded into recency recurrence:
    // ws = 0.7*ws + new  (Horner form of the einsum; fp64 diff ~1ulp, safe)
    #pragma unroll
    for (int i = 0; i < 32; ++i) {
      double v = s[i];
      v = (fabs(v) >= 0.01) ? v : 0.0;
      ws[i] = ws[i] * 0.7 + v * 0.9;
    }
    nrm = nrm * 0.7 + 1.0;           // w.sum(): 1, 1.7, 2.19, 2.533
    const double inv = 1.0 / nrm;    // uniform; mul instead of 32 divides

    // h = relu(st @ Wenc^T + benc).  k-outer / c-inner: each h[c] is still a
    // single ascending-k fma chain; avoids an st[32] register array.
    double h[16];
    #pragma unroll
    for (int c = 0; c < 16; ++c) h[c] = 0.0;
    #pragma unroll
    for (int k = 0; k < 32; ++k) {
      double stk = ws[k] * inv;
      #pragma unroll
      for (int c = 0; c < 16; ++c)
        h[c] = fma(stk, sWenc[c * 32 + k], h[c]);
    }
    #pragma unroll
    for (int c = 0; c < 16; ++c) h[c] = fmax(h[c] + sBenc[c], 0.0);

    // rec = h @ Wdec^T + bdec; importance threshold 0.05
    #pragma unroll
    for (int i = 0; i < 32; ++i) {
      double acc = 0.0;
      #pragma unroll
      for (int c = 0; c < 16; ++c)
        acc = fma(h[c], sWdec[i * 16 + c], acc);
      acc = acc + sBdec[i];
      s[i] = (fabs(acc) >= 0.05) ? acc : 0.0;
    }

    // top-8 of 32 |s| via branchless insertion ladder; keep |s| >= kth
    double top[8];
    #pragma unroll
    for (int k = 0; k < 8; ++k) top[k] = 0.0;
    #pragma unroll
    for (int i = 0; i < 32; ++i) {
      double v = fabs(s[i]);
      #pragma unroll
      for (int k = 0; k < 8; ++k) {
        double hi = fmax(top[k], v);
        v = fmin(top[k], v);
        top[k] = hi;
      }
    }
    double kth = top[7];
    #pragma unroll
    for (int i = 0; i < 32; ++i)
      s[i] = (fabs(s[i]) >= kth) ? s[i] : 0.0;
  }

  float4* dst = reinterpret_cast<float4*>(out + STATES_OFF) + (size_t)n * 8;
  #pragma unroll
  for (int j = 0; j < 8; ++j)
    dst[j] = make_float4((float)s[4 * j + 0], (float)s[4 * j + 1],
                         (float)s[4 * j + 2], (float)s[4 * j + 3]);
}

extern "C" void kernel_launch(void* const* d_in, const int* in_sizes, int n_in,
                              void* d_out, int out_size, void* d_ws, size_t ws_size,
                              hipStream_t stream) {
  const float* x    = (const float*)d_in[0];
  const float* ns   = (const float*)d_in[1];
  const float* Wenc = (const float*)d_in[2];
  const float* benc = (const float*)d_in[3];
  const float* Wdec = (const float*)d_in[4];
  const float* bdec = (const float*)d_in[5];
  float* out = (float*)d_out;

  enn_states_f64_kernel<<<N_NEURONS / 256, 256, 0, stream>>>(ns, Wenc, benc,
                                                             Wdec, bdec, out);
  tanh4_kernel<<<X4 / 256, 256, 0, stream>>>(x, out);
}

// Round 4
// 692.893 us; speedup vs baseline: 2.2385x; 2.2385x over previous
//
#include <hip/hip_runtime.h>

// Problem constants (fixed by reference)
constexpr int N_NEURONS  = 131072;
constexpr int X_ELEMS    = 4 * 131072 * 32;   // 16,777,216
constexpr int X4         = X_ELEMS / 4;       // 4,194,304 float4
constexpr int STATES_OFF = X_ELEMS;           // states start after x in d_out

// Fast tanh: t = 1 - 2/(e^{2|x|}+1), sign restored. Overflow-clean.
// Abs error ~1e-6 vs libm; output-0 threshold 2.5e-2. (Passed R1-R3.)
__device__ __forceinline__ float fast_tanh(float x) {
  float a = fabsf(x);
  float e = __expf(2.0f * a);
  float t = 1.0f - __fdividef(2.0f, e + 1.0f);
  return copysignf(t, x);
}

__global__ __launch_bounds__(256) void tanh4_kernel(const float* __restrict__ x,
                                                    float* __restrict__ out) {
  int idx = blockIdx.x * 256 + threadIdx.x;
  float4 v = reinterpret_cast<const float4*>(x)[idx];
  #pragma unroll
  for (int k = 0; k < 4; ++k) {
    v.x = fast_tanh(v.x);
    v.y = fast_tanh(v.y);
    v.z = fast_tanh(v.z);
    v.w = fast_tanh(v.w);
  }
  reinterpret_cast<float4*>(out)[idx] = v;
}

__device__ __forceinline__ double shfl_xor_d(double v, int mask) {
  return __shfl_xor(v, mask, 64);
}

// States path in FP64, TWO lanes per neuron (16 states each) so all arrays
// stay in registers (R3: one-lane version demoted arrays to scratch -> 2.9 GB
// of HBM spill traffic, 1.4 ms). Cross-lane: h-partial butterfly (commutative
// fp64 add -> both lanes bitwise equal) and top-8 merge via snapshot+insert.
__global__ __launch_bounds__(256) void enn_states_f64_kernel(
    const float* __restrict__ ns, const float* __restrict__ Wenc,
    const float* __restrict__ benc, const float* __restrict__ Wdec,
    const float* __restrict__ bdec, float* __restrict__ out) {
  __shared__ double sWenc[16 * 32];
  __shared__ double sWdec[32 * 16];
  __shared__ double sBenc[16];
  __shared__ double sBdec[32];

  const int tid = threadIdx.x;
  #pragma unroll
  for (int i = tid; i < 512; i += 256) {
    sWenc[i] = (double)Wenc[i];
    sWdec[i] = (double)Wdec[i];
  }
  if (tid < 16) sBenc[tid] = (double)benc[tid];
  if (tid < 32) sBdec[tid] = (double)bdec[tid];
  __syncthreads();

  const int gtid = blockIdx.x * 256 + tid;
  const int n    = gtid >> 1;          // neuron
  const int soff = (tid & 1) * 16;     // this lane's state offset (0 or 16)

  double s[16], ws[16];
  const float4* src =
      reinterpret_cast<const float4*>(ns) + (size_t)n * 8 + (soff >> 2);
  #pragma unroll
  for (int j = 0; j < 4; ++j) {
    float4 v = src[j];
    s[4 * j + 0] = (double)v.x; s[4 * j + 1] = (double)v.y;
    s[4 * j + 2] = (double)v.z; s[4 * j + 3] = (double)v.w;
  }
  #pragma unroll
  for (int i = 0; i < 16; ++i) ws[i] = 0.0;

  double nrm = 0.0;
  #pragma unroll 1   // rolled: keep code small for I-cache
  for (int layer = 0; layer < 4; ++layer) {
    // sparsity (|s|>=0.01) + decay *0.9 folded into recency recurrence
    #pragma unroll
    for (int i = 0; i < 16; ++i) {
      double v = s[i];
      v = (fabs(v) >= 0.01) ? v : 0.0;
      ws[i] = ws[i] * 0.7 + v * 0.9;
    }
    nrm = nrm * 0.7 + 1.0;           // w.sum(): 1, 1.7, 2.19, 2.533
    const double inv = 1.0 / nrm;

    // h = relu(st @ Wenc^T + benc): each lane does its 16-k partial,
    // butterfly-add with partner lane, then bias+relu (identical in both).
    double h[16];
    #pragma unroll
    for (int c = 0; c < 16; ++c) h[c] = 0.0;
    #pragma unroll
    for (int k = 0; k < 16; ++k) {
      double stk = ws[k] * inv;
      #pragma unroll
      for (int c = 0; c < 16; ++c)
        h[c] = fma(stk, sWenc[c * 32 + soff + k], h[c]);
    }
    #pragma unroll
    for (int c = 0; c < 16; ++c) {
      h[c] = h[c] + shfl_xor_d(h[c], 1);   // full k=32 sum, both lanes
      h[c] = fmax(h[c] + sBenc[c], 0.0);
    }

    // rec = h @ Wdec^T + bdec for this lane's 16 states; threshold 0.05
    #pragma unroll
    for (int i = 0; i < 16; ++i) {
      double acc = 0.0;
      #pragma unroll
      for (int c = 0; c < 16; ++c)
        acc = fma(h[c], sWdec[(soff + i) * 16 + c], acc);
      acc = acc + sBdec[soff + i];
      s[i] = (fabs(acc) >= 0.05) ? acc : 0.0;
    }

    // top-8 of the 32 |s| (split across the lane pair):
    // local sorted top-8 ladder, snapshot partner's ladder, insert.
    double top[8];
    #pragma unroll
    for (int k = 0; k < 8; ++k) top[k] = 0.0;
    #pragma unroll
    for (int i = 0; i < 16; ++i) {
      double v = fabs(s[i]);
      #pragma unroll
      for (int k = 0; k < 8; ++k) {
        double hi = fmax(top[k], v);
        v = fmin(top[k], v);
        top[k] = hi;
      }
    }
    double oth[8];
    #pragma unroll
    for (int k = 0; k < 8; ++k) oth[k] = shfl_xor_d(top[k], 1);  // pre-merge
    #pragma unroll
    for (int m = 0; m < 8; ++m) {
      double v = oth[m];
      #pragma unroll
      for (int k = 0; k < 8; ++k) {
        double hi = fmax(top[k], v);
        v = fmin(top[k], v);
        top[k] = hi;
      }
    }
    double kth = top[7];   // 8th largest of all 32; same in both lanes
    #pragma unroll
    for (int i = 0; i < 16; ++i)
      s[i] = (fabs(s[i]) >= kth) ? s[i] : 0.0;
  }

  float4* dst = reinterpret_cast<float4*>(out + STATES_OFF) +
                (size_t)n * 8 + (soff >> 2);
  #pragma unroll
  for (int j = 0; j < 4; ++j)
    dst[j] = make_float4((float)s[4 * j + 0], (float)s[4 * j + 1],
                         (float)s[4 * j + 2], (float)s[4 * j + 3]);
}

extern "C" void kernel_launch(void* const* d_in, const int* in_sizes, int n_in,
                              void* d_out, int out_size, void* d_ws, size_t ws_size,
                              hipStream_t stream) {
  const float* x    = (const float*)d_in[0];
  const float* ns   = (const float*)d_in[1];
  const float* Wenc = (const float*)d_in[2];
  const float* benc = (const float*)d_in[3];
  const float* Wdec = (const float*)d_in[4];
  const float* bdec = (const float*)d_in[5];
  float* out = (float*)d_out;

  enn_states_f64_kernel<<<N_NEURONS * 2 / 256, 256, 0, stream>>>(
      ns, Wenc, benc, Wdec, bdec, out);
  tanh4_kernel<<<X4 / 256, 256, 0, stream>>>(x, out);
}

// Round 5
// 490.125 us; speedup vs baseline: 3.1646x; 1.4137x over previous
//
#include <hip/hip_runtime.h>

// Problem constants (fixed by reference)
constexpr int N_NEURONS  = 131072;
constexpr int X_ELEMS    = 4 * 131072 * 32;   // 16,777,216
constexpr int X4         = X_ELEMS / 4;       // 4,194,304 float4
constexpr int STATES_OFF = X_ELEMS;           // states start after x in d_out

// Fast tanh: t = 1 - 2/(e^{2|x|}+1), sign restored. Overflow-clean.
// Abs error ~1e-6 vs libm; output-0 threshold 2.5e-2. (Passed R1-R4.)
__device__ __forceinline__ float fast_tanh(float x) {
  float a = fabsf(x);
  float e = __expf(2.0f * a);
  float t = 1.0f - __fdividef(2.0f, e + 1.0f);
  return copysignf(t, x);
}

__global__ __launch_bounds__(256) void tanh4_kernel(const float* __restrict__ x,
                                                    float* __restrict__ out) {
  int idx = blockIdx.x * 256 + threadIdx.x;
  float4 v = reinterpret_cast<const float4*>(x)[idx];
  #pragma unroll
  for (int k = 0; k < 4; ++k) {
    v.x = fast_tanh(v.x);
    v.y = fast_tanh(v.y);
    v.z = fast_tanh(v.z);
    v.w = fast_tanh(v.w);
  }
  reinterpret_cast<float4*>(out)[idx] = v;
}

__device__ __forceinline__ double shfl_xor_d(double v, int mask) {
  return __shfl_xor(v, mask, 64);
}

// States path in FP64, FOUR lanes per neuron (8 states each). R4's 2-lane
// version still spilled (VGPR=256, 2.3 GB scratch traffic): 64 live doubles
// + hipcc's LDS-prefetch hoisting blew the cap. 4-lane halves both the live
// arrays (48 doubles) and every unrolled fma block. Cross-lane glue:
// 2-stage butterflies; fp64 add commutative -> all 4 lanes bitwise equal.
__global__ __launch_bounds__(256) void enn_states_f64_kernel(
    const float* __restrict__ ns, const float* __restrict__ Wenc,
    const float* __restrict__ benc, const float* __restrict__ Wdec,
    const float* __restrict__ bdec, float* __restrict__ out) {
  __shared__ double sWenc[16 * 32];
  __shared__ double sWdec[32 * 16];
  __shared__ double sBenc[16];
  __shared__ double sBdec[32];

  const int tid = threadIdx.x;
  #pragma unroll
  for (int i = tid; i < 512; i += 256) {
    sWenc[i] = (double)Wenc[i];
    sWdec[i] = (double)Wdec[i];
  }
  if (tid < 16) sBenc[tid] = (double)benc[tid];
  if (tid < 32) sBdec[tid] = (double)bdec[tid];
  __syncthreads();

  const int gtid = blockIdx.x * 256 + tid;
  const int n    = gtid >> 2;          // neuron
  const int soff = (tid & 3) * 8;      // this lane's state offset (0/8/16/24)

  double s[8], ws[8];
  const float4* src =
      reinterpret_cast<const float4*>(ns) + (size_t)n * 8 + (soff >> 2);
  #pragma unroll
  for (int j = 0; j < 2; ++j) {
    float4 v = src[j];
    s[4 * j + 0] = (double)v.x; s[4 * j + 1] = (double)v.y;
    s[4 * j + 2] = (double)v.z; s[4 * j + 3] = (double)v.w;
  }
  #pragma unroll
  for (int i = 0; i < 8; ++i) ws[i] = 0.0;

  double nrm = 0.0;
  #pragma unroll 1   // rolled: keep code small for I-cache
  for (int layer = 0; layer < 4; ++layer) {
    // sparsity (|s|>=0.01) + decay *0.9 folded into recency recurrence
    #pragma unroll
    for (int i = 0; i < 8; ++i) {
      double v = s[i];
      v = (fabs(v) >= 0.01) ? v : 0.0;
      ws[i] = ws[i] * 0.7 + v * 0.9;
    }
    nrm = nrm * 0.7 + 1.0;           // w.sum(): 1, 1.7, 2.19, 2.533
    const double inv = 1.0 / nrm;

    // h = relu(st @ Wenc^T + benc): each lane does its 8-k partial,
    // 2-stage butterfly (xor1, xor2) -> full k=32 sum in all 4 lanes
    // (fp64 add commutative at each stage -> bitwise identical).
    double h[16];
    #pragma unroll
    for (int c = 0; c < 16; ++c) h[c] = 0.0;
    #pragma unroll
    for (int k = 0; k < 8; ++k) {
      double stk = ws[k] * inv;
      #pragma unroll
      for (int c = 0; c < 16; ++c)
        h[c] = fma(stk, sWenc[c * 32 + soff + k], h[c]);
    }
    #pragma unroll
    for (int c = 0; c < 16; ++c) {
      h[c] = h[c] + shfl_xor_d(h[c], 1);
      h[c] = h[c] + shfl_xor_d(h[c], 2);
      h[c] = fmax(h[c] + sBenc[c], 0.0);
    }

    // rec = h @ Wdec^T + bdec for this lane's 8 states; threshold 0.05
    #pragma unroll
    for (int i = 0; i < 8; ++i) {
      double acc = 0.0;
      #pragma unroll
      for (int c = 0; c < 16; ++c)
        acc = fma(h[c], sWdec[(soff + i) * 16 + c], acc);
      acc = acc + sBdec[soff + i];
      s[i] = (fabs(acc) >= 0.05) ? acc : 0.0;
    }

    // top-8 of the 32 |s| (split across 4 lanes): local sorted ladder,
    // then snapshot+insert merge at xor1 and xor2. Identical multiset at
    // each stage -> identical sorted ladder -> identical kth in all lanes.
    double top[8];
    #pragma unroll
    for (int k = 0; k < 8; ++k) top[k] = 0.0;
    #pragma unroll
    for (int i = 0; i < 8; ++i) {
      double v = fabs(s[i]);
      #pragma unroll
      for (int k = 0; k < 8; ++k) {
        double hi = fmax(top[k], v);
        v = fmin(top[k], v);
        top[k] = hi;
      }
    }
    #pragma unroll
    for (int stage = 1; stage <= 2; stage <<= 1) {
      double oth[8];
      #pragma unroll
      for (int k = 0; k < 8; ++k) oth[k] = shfl_xor_d(top[k], stage);
      #pragma unroll
      for (int m = 0; m < 8; ++m) {
        double v = oth[m];
        #pragma unroll
        for (int k = 0; k < 8; ++k) {
          double hi = fmax(top[k], v);
          v = fmin(top[k], v);
          top[k] = hi;
        }
      }
    }
    double kth = top[7];   // 8th largest of all 32; same in all 4 lanes
    #pragma unroll
    for (int i = 0; i < 8; ++i)
      s[i] = (fabs(s[i]) >= kth) ? s[i] : 0.0;
  }

  float4* dst = reinterpret_cast<float4*>(out + STATES_OFF) +
                (size_t)n * 8 + (soff >> 2);
  #pragma unroll
  for (int j = 0; j < 2; ++j)
    dst[j] = make_float4((float)s[4 * j + 0], (float)s[4 * j + 1],
                         (float)s[4 * j + 2], (float)s[4 * j + 3]);
}

extern "C" void kernel_launch(void* const* d_in, const int* in_sizes, int n_in,
                              void* d_out, int out_size, void* d_ws, size_t ws_size,
                              hipStream_t stream) {
  const float* x    = (const float*)d_in[0];
  const float* ns   = (const float*)d_in[1];
  const float* Wenc = (const float*)d_in[2];
  const float* benc = (const float*)d_in[3];
  const float* Wdec = (const float*)d_in[4];
  const float* bdec = (const float*)d_in[5];
  float* out = (float*)d_out;

  enn_states_f64_kernel<<<N_NEURONS * 4 / 256, 256, 0, stream>>>(
      ns, Wenc, benc, Wdec, bdec, out);
  tanh4_kernel<<<X4 / 256, 256, 0, stream>>>(x, out);
}